// Round 1
// baseline (265.799 us; speedup 1.0000x reference)
//
#include <hip/hip_runtime.h>
#include <hip/hip_bf16.h>
#include <math.h>

typedef short bf16x8 __attribute__((ext_vector_type(8)));
typedef float f32x4 __attribute__((ext_vector_type(4)));

static __device__ __forceinline__ unsigned short f2bf(float f) {
    unsigned int u = __float_as_uint(f);
    unsigned int r = (u + 0x7fffu + ((u >> 16) & 1u)) >> 16;
    return (unsigned short)r;
}

// elementwise square of a bf16x8 fragment (bf16 -> f32 -> square -> bf16 rne)
static __device__ __forceinline__ bf16x8 sq_bf16x8(bf16x8 a) {
    bf16x8 r;
    #pragma unroll
    for (int i = 0; i < 8; ++i) {
        unsigned int u = ((unsigned int)(unsigned short)a[i]) << 16;
        float f = __uint_as_float(u);
        f *= f;
        r[i] = (short)f2bf(f);
    }
    return r;
}

static __device__ __forceinline__ float gelu_f(float x) {
    return 0.5f * x * (1.f + erff(x * 0.70710678118654752f));
}

// async global->LDS, 16B per lane; LDS dest is wave-uniform base + lane*16
static __device__ __forceinline__ void gload_lds16(const void* g, void* l) {
    __builtin_amdgcn_global_load_lds(
        (const __attribute__((address_space(1))) unsigned int*)g,
        (__attribute__((address_space(3))) unsigned int*)l, 16, 0, 0);
}

// LDS index skew for FFT buffers
static __device__ __forceinline__ int ldsmap(int i) { return i + (i >> 6); }

static __device__ __forceinline__ int rev4(int k) {
    int d0 = k % 10; k /= 10;
    int d1 = k % 10; k /= 10;
    int d2 = k % 10; int d3 = k / 10;
    return d0 * 1000 + d1 * 100 + d2 * 10 + d3;
}

// ---------------------------------------------------------------------------
// Per-launch constant tables (workspace is re-poisoned each run):
//  idxTab[k] (k in 0..10000): packed u16 pair (ldsmap(rev4(k1)), ldsmap(rev4(k2)))
//  twTab[m]  (m in 0..8991):  exp(-2*pi*i*m/10000) as float2 (cos, sin)
// Replaces per-bin rev4 integer-div chains and per-butterfly sincos+recurrence
// in the VALU-bound FFT kernel with L2-resident lookups.
// ---------------------------------------------------------------------------
__global__ __launch_bounds__(256)
void init_tables_kernel(unsigned int* __restrict__ idxTab, float2* __restrict__ twTab)
{
    int i = blockIdx.x * 256 + threadIdx.x;
    if (i < 10001) {
        int k1 = (i == 10000) ? 0 : i;
        int k2 = (k1 == 0) ? 0 : 10000 - k1;
        unsigned a = (unsigned)ldsmap(rev4(k1));
        unsigned b = (unsigned)ldsmap(rev4(k2));
        idxTab[i] = a | (b << 16);
    }
    if (i < 8992) {
        float ang = (float)i * -6.28318530717958648e-4f;
        float s, c;
        __sincosf(ang, &s, &c);
        twTab[i] = make_float2(c, s);
    }
}

// forward 5-point DFT (W5 = e^{-2pi i/5}), Winograd-style
static __device__ __forceinline__ void dft5(
    float a0r, float a0i, float a1r, float a1i, float a2r, float a2i,
    float a3r, float a3i, float a4r, float a4i,
    float* Xr, float* Xi)
{
    const float c1 = 0.30901699437494742f, c2 = -0.80901699437494745f;
    const float s1 = 0.95105651629515357f, s2 = 0.58778525229247312f;
    float t1r = a1r + a4r, t1i = a1i + a4i;
    float d1r = a1r - a4r, d1i = a1i - a4i;
    float t2r = a2r + a3r, t2i = a2i + a3i;
    float d2r = a2r - a3r, d2i = a2i - a3i;
    Xr[0] = a0r + t1r + t2r; Xi[0] = a0i + t1i + t2i;
    float m1r = a0r + c1 * t1r + c2 * t2r, m1i = a0i + c1 * t1i + c2 * t2i;
    float m2r = a0r + c2 * t1r + c1 * t2r, m2i = a0i + c2 * t1i + c1 * t2i;
    float n1r = s1 * d1r + s2 * d2r, n1i = s1 * d1i + s2 * d2i;
    float n2r = s2 * d1r - s1 * d2r, n2i = s2 * d1i - s1 * d2i;
    Xr[1] = m1r + n1i; Xi[1] = m1i - n1r;
    Xr[4] = m1r - n1i; Xi[4] = m1i + n1r;
    Xr[2] = m2r + n2i; Xi[2] = m2i - n2r;
    Xr[3] = m2r - n2i; Xi[3] = m2i + n2r;
}

// core of a radix-10 DIF butterfly given 10 loaded taps; writes LDS (twiddled)
// twiddles come from the global table: tw[t] = twTab[j*SC*t], max index 8991
template<int S>
static __device__ __forceinline__ void radix10_core(
    float* __restrict__ reb, float* __restrict__ imb,
    const float* ar, const float* ai, int base, int j,
    const float2* __restrict__ twTab)
{
    constexpr int L  = (S == 0) ? 1000 : (S == 1) ? 100 : (S == 2) ? 10 : 1;
    constexpr int SC = (S == 0) ? 1 : (S == 1) ? 10 : (S == 2) ? 100 : 1000;
    constexpr bool TW = (S != 3);

    const float WR[5] = {1.f, 0.80901699437494745f, 0.30901699437494742f,
                         -0.30901699437494742f, -0.80901699437494745f};
    const float WI[5] = {0.f, -0.58778525229247312f, -0.95105651629515357f,
                         -0.95105651629515357f, -0.58778525229247312f};

    float Er[5], Ei[5], Or[5], Oi[5];
    dft5(ar[0], ai[0], ar[2], ai[2], ar[4], ai[4], ar[6], ai[6], ar[8], ai[8], Er, Ei);
    dft5(ar[1], ai[1], ar[3], ai[3], ar[5], ai[5], ar[7], ai[7], ar[9], ai[9], Or, Oi);
    #pragma unroll
    for (int k = 1; k < 5; ++k) {
        float tr = Or[k] * WR[k] - Oi[k] * WI[k];
        Oi[k] = Or[k] * WI[k] + Oi[k] * WR[k];
        Or[k] = tr;
    }

    if (TW) {
        const int js = j * SC;
        float twr[10], twi[10];
        #pragma unroll
        for (int t = 1; t < 10; ++t) {
            float2 wv_ = twTab[js * t];
            twr[t] = wv_.x; twi[t] = wv_.y;
        }
        #pragma unroll
        for (int k = 0; k < 5; ++k) {
            float xr0 = Er[k] + Or[k], xi0 = Ei[k] + Oi[k];
            float xr1 = Er[k] - Or[k], xi1 = Ei[k] - Oi[k];
            int i0 = ldsmap(base + k * L);
            int i1 = ldsmap(base + (k + 5) * L);
            if (k == 0) {
                reb[i0] = xr0;
                imb[i0] = xi0;
            } else {
                reb[i0] = xr0 * twr[k] - xi0 * twi[k];
                imb[i0] = xr0 * twi[k] + xi0 * twr[k];
            }
            reb[i1] = xr1 * twr[k + 5] - xi1 * twi[k + 5];
            imb[i1] = xr1 * twi[k + 5] + xi1 * twr[k + 5];
        }
    } else {
        #pragma unroll
        for (int k = 0; k < 5; ++k) {
            int i0 = ldsmap(base + k * L);
            int i1 = ldsmap(base + (k + 5) * L);
            reb[i0] = Er[k] + Or[k]; imb[i0] = Ei[k] + Oi[k];
            reb[i1] = Er[k] - Or[k]; imb[i1] = Ei[k] - Oi[k];
        }
    }
}

// radix-10 DIF stage for S>=1 (reads LDS)
template<int S>
static __device__ __forceinline__ void radix10_stage(
    float* __restrict__ reb, float* __restrict__ imb, int tid,
    const float2* __restrict__ twTab)
{
    constexpr int L = (S == 1) ? 100 : (S == 2) ? 10 : 1;
    for (int w = tid; w < 1000; w += 512) {
        int g, j;
        if (S == 3) { g = w; j = 0; }
        else        { g = w / L; j = w - g * L; }
        const int base = g * (10 * L) + j;
        float ar[10], ai[10];
        #pragma unroll
        for (int u = 0; u < 10; ++u) {
            int idx = ldsmap(base + u * L);
            ar[u] = reb[idx];
            ai[u] = imb[idx];
        }
        radix10_core<S>(reb, imb, ar, ai, base, j, twTab);
    }
}

// ---------------------------------------------------------------------------
// Fused FFT + prep. Blocks [0,1024): FFT rows (512 thr, 1 row/block, 81 KB
// LDS, 2 blocks/CU). Mean-subtraction eliminated algebraically (affects only
// bin 0, where centered X[0]=0 exactly -> h[0]=0 forced). Stage 0 fused with
// the global load. Twiddles + untangle indices come from tables; untangle's
// per-bin sincos replaced by a per-thread rotor recurrence (stride-512 step).
// Blocks [1024,3804): weight prep.
// ---------------------------------------------------------------------------
__global__ __launch_bounds__(512, 4)
void fft_prep_kernel(const float* __restrict__ x,
                     unsigned short* __restrict__ hb,
                     float* __restrict__ hnorm,
                     const float* __restrict__ W0, const float* __restrict__ A0,
                     unsigned short* __restrict__ Wb, unsigned short* __restrict__ Sb,
                     const float* __restrict__ W1, const float* __restrict__ A1,
                     const float* __restrict__ W2, const float* __restrict__ A2,
                     float* __restrict__ W1T, float* __restrict__ S1T,
                     float* __restrict__ W2T, float* __restrict__ S2T,
                     const unsigned int* __restrict__ idxTab,
                     const float2* __restrict__ twTab)
{
    if (blockIdx.x >= 1024) {
        // ---- prep path ----
        int idx = (blockIdx.x - 1024) * 512 + threadIdx.x;
        if (idx < 1280128) {
            const bool isW = idx < 640064;
            const int f4 = isW ? idx : idx - 640064;
            const float* src = isW ? W0 : A0;
            unsigned short* dst = isW ? Wb : Sb;
            float4 v = ((const float4*)src)[f4];
            float e[4] = {v.x, v.y, v.z, v.w};
            int flat = f4 * 4;
            int row = flat / 10001;
            int col = flat - row * 10001;
            #pragma unroll
            for (int i = 0; i < 4; ++i) {
                if (col == 10001) { row++; col = 0; }
                float val = isW ? e[i] : 1.f / (1.f + expf(-e[i]));
                dst[(size_t)row * 10240 + col] = f2bf(val);
                col++;
            }
        } else if (idx < 1341312) {
            int i = idx - 1280128;              // 256*239 pads
            int row = i / 239;
            int col = 10001 + (i - row * 239);
            Wb[(size_t)row * 10240 + col] = 0;
            Sb[(size_t)row * 10240 + col] = 0;
        } else if (idx < 1423232) {
            int o = idx - 1341312;              // 0..81919
            if (o < 32768) {
                int d = o >> 7, h = o & 127;
                W1T[o] = W1[h * 256 + d];
            } else if (o < 65536) {
                int p = o - 32768;
                int d = p >> 7, h = p & 127;
                S1T[p] = 1.f / (1.f + expf(-A1[h * 256 + d]));
            } else if (o < 73728) {
                int p = o - 65536;
                int d = p >> 6, h = p & 63;
                W2T[p] = W2[h * 128 + d];
            } else {
                int p = o - 73728;
                int d = p >> 6, h = p & 63;
                S2T[p] = 1.f / (1.f + expf(-A2[h * 128 + d]));
            }
        }
        return;
    }

    // ---- FFT path ----
    __shared__ float reb[10156];
    __shared__ float imb[10156];
    __shared__ float redbuf[8];

    const int b = blockIdx.x;
    const int tid = threadIdx.x;
    const int lane = tid & 63;
    const int wv = tid >> 6;

    // stage 0 fused with global load: z[n] = (x[2n], x[2n+1]) as float2
    const float2* z2 = (const float2*)(x + (size_t)b * 20000);
    for (int w = tid; w < 1000; w += 512) {
        float ar[10], ai[10];
        #pragma unroll
        for (int u = 0; u < 10; ++u) {
            float2 v = z2[w + u * 1000];
            ar[u] = v.x; ai[u] = v.y;
        }
        radix10_core<0>(reb, imb, ar, ai, w, w, twTab);
    }
    __syncthreads();
    radix10_stage<1>(reb, imb, tid, twTab);
    __syncthreads();
    radix10_stage<2>(reb, imb, tid, twTab);
    __syncthreads();
    radix10_stage<3>(reb, imb, tid, twTab);
    __syncthreads();

    // real-FFT untangle + log(1+|X|); h[0]=0 exactly (centered DC bin).
    // (ct,st) = exp(-i*pi*k/10000) advanced by a constant rotor per i-step
    // (k += 512): cos/sin(-512*pi/10000) = (0.987091579, -0.160156842).
    float ct, st;
    __sincosf((float)tid * -3.14159265358979324e-4f, &st, &ct);
    const float RC = 0.987091579f;
    const float RS = -0.160156842f;
    float sumsq = 0.f;
    unsigned short* hrow = hb + (size_t)b * 10240;
    #pragma unroll
    for (int i = 0; i < 20; ++i) {
        int k = tid + i * 512;
        float hval = 0.f;
        if (k > 0 && k <= 10000) {
            unsigned pp = idxTab[k];
            int i1 = (int)(pp & 0xffffu);
            int i2 = (int)(pp >> 16);
            float zr = reb[i1], zi = imb[i1];
            float wr = reb[i2], wi = imb[i2];
            float er = 0.5f * (zr + wr);
            float ei = 0.5f * (zi - wi);
            float odr = 0.5f * (zi + wi);
            float odi = -0.5f * (zr - wr);
            float xre = er + ct * odr - st * odi;
            float xim = ei + ct * odi + st * odr;
            hval = __logf(1.f + sqrtf(xre * xre + xim * xim));
        }
        hrow[k] = f2bf(hval);
        sumsq += hval * hval;
        // advance rotor (use old ct for both products)
        float nct = ct * RC - st * RS;
        st = ct * RS + st * RC;
        ct = nct;
    }
    #pragma unroll
    for (int o = 32; o; o >>= 1) sumsq += __shfl_xor(sumsq, o);
    __syncthreads();
    if (lane == 0) redbuf[wv] = sumsq;
    __syncthreads();
    if (tid == 0) {
        float tsq = 0.f;
        #pragma unroll
        for (int i = 0; i < 8; ++i) tsq += redbuf[i];
        hnorm[b] = 1.f / (sqrtf(tsq) + 1e-8f);
    }
}

// ---------------------------------------------------------------------------
// Layer-0 dual GEMM: Y = h*W0^T, P = (h^2)*S0^T (1/||h|| applied downstream).
// BM=128 BN=64 BK=64, split-K=16. Linear grid 512 with XCD-aware decode:
// XCD c (= lin%8, round-robin dispatch) owns k-slices z in {2c, 2c+1}, so the
// per-XCD live operand footprint (2*1.25MB A-slices + 1.25MB B-slices) fits
// the 4MB per-XCD L2 -> A/B re-reads become L2 hits instead of HBM refetch.
// 3 blocks/CU (acc+frags ~150 VGPR < 512/3) to cover vmcnt(0) barrier drains.
// ---------------------------------------------------------------------------
__global__ __launch_bounds__(256, 3)
void gemm0_kernel(const unsigned short* __restrict__ hb,
                  const unsigned short* __restrict__ Wb, const unsigned short* __restrict__ Sb,
                  float* __restrict__ Py, float* __restrict__ Pp)
{
    __shared__ unsigned short Ah[128 * 64];
    __shared__ unsigned short Bw[64 * 64];
    __shared__ unsigned short Bs[64 * 64];

    const int t = threadIdx.x;
    // bijective decode: lin -> (xcd, z, m-tile, n-tile)
    const int lin = blockIdx.x;           // 0..511
    const int xcd = lin & 7;
    const int sub = lin >> 3;             // 0..63
    const int z = xcd * 2 + (sub & 1);    // 0..15, z-pair per XCD
    const int tile = sub >> 1;            // 0..31
    const int b0 = (tile & 7) * 128;
    const int n0 = (tile >> 3) * 64;

    const int lane = t & 63;
    const int wv = t >> 6;
    const int ml = lane & 15;
    const int q4 = lane >> 4;
    const int s0 = q4 ^ (ml & 7);

    const int sub8 = lane >> 3;
    const int sl = lane & 7;
    const int gsw = sl ^ sub8;

    f32x4 accY[2][4], accP[2][4];
    #pragma unroll
    for (int mt = 0; mt < 2; ++mt)
        #pragma unroll
        for (int nt = 0; nt < 4; ++nt) {
            accY[mt][nt] = (f32x4){0.f, 0.f, 0.f, 0.f};
            accP[mt][nt] = (f32x4){0.f, 0.f, 0.f, 0.f};
        }

    const int kbase = z * 640;

    for (int step = 0; step < 10; ++step) {
        const int k0 = kbase + step * 64;
        __syncthreads();
        #pragma unroll
        for (int j = 0; j < 4; ++j) {
            const int c = wv * 4 + j;
            const size_t go = (size_t)(b0 + c * 8 + sub8) * 10240 + k0 + gsw * 8;
            gload_lds16(&hb[go], &Ah[c * 512]);
        }
        #pragma unroll
        for (int j = 0; j < 2; ++j) {
            const int c = wv * 2 + j;
            const size_t go = (size_t)(n0 + c * 8 + sub8) * 10240 + k0 + gsw * 8;
            gload_lds16(&Wb[go], &Bw[c * 512]);
            gload_lds16(&Sb[go], &Bs[c * 512]);
        }
        __syncthreads();

        #pragma unroll
        for (int kk = 0; kk < 2; ++kk) {
            const int slot = (s0 ^ (kk << 2)) << 3;
            bf16x8 ah[2], ac[2], bw[4], bs[4];
            #pragma unroll
            for (int mt = 0; mt < 2; ++mt) {
                int mrow = wv * 32 + mt * 16 + ml;
                ah[mt] = *(const bf16x8*)&Ah[mrow * 64 + slot];
                ac[mt] = sq_bf16x8(ah[mt]);
            }
            #pragma unroll
            for (int nt = 0; nt < 4; ++nt) {
                int nrow = nt * 16 + ml;
                bw[nt] = *(const bf16x8*)&Bw[nrow * 64 + slot];
                bs[nt] = *(const bf16x8*)&Bs[nrow * 64 + slot];
            }
            #pragma unroll
            for (int mt = 0; mt < 2; ++mt)
                #pragma unroll
                for (int nt = 0; nt < 4; ++nt) {
                    accY[mt][nt] = __builtin_amdgcn_mfma_f32_16x16x32_bf16(ah[mt], bw[nt], accY[mt][nt], 0, 0, 0);
                    accP[mt][nt] = __builtin_amdgcn_mfma_f32_16x16x32_bf16(ac[mt], bs[nt], accP[mt][nt], 0, 0, 0);
                }
        }
    }

    const int rq = q4 * 4;
    #pragma unroll
    for (int mt = 0; mt < 2; ++mt)
        #pragma unroll
        for (int nt = 0; nt < 4; ++nt)
            #pragma unroll
            for (int r = 0; r < 4; ++r) {
                int m = b0 + wv * 32 + mt * 16 + rq + r;
                int n = n0 + nt * 16 + ml;
                size_t o = ((size_t)z * 1024 + m) * 256 + n;
                Py[o] = accY[mt][nt][r];
                Pp[o] = accP[mt][nt][r];
            }
}

// ---------------------------------------------------------------------------
// Fused combine + tail: split-K reduce + layer-0 plastic/LN/GELU (in LDS),
// then layers 1,2 + head. 2 rows per block, grid 512 x 256 thr
// (2 blocks/CU = 2 waves/SIMD -> 2x latency hiding vs the old 256-block
// 1-wave/SIMD launch; layer-2's d-loop is split across all 4 waves).
// ---------------------------------------------------------------------------
__global__ __launch_bounds__(256)
void combine_tail_kernel(const float* __restrict__ Py, const float* __restrict__ Pp,
                 const float* __restrict__ hnorm,
                 const float* __restrict__ b0v, const float* __restrict__ eta0p,
                 const float* __restrict__ g0, const float* __restrict__ be0,
                 const float* __restrict__ W1T, const float* __restrict__ S1T,
                 const float* __restrict__ b1, const float* __restrict__ eta1p,
                 const float* __restrict__ g1, const float* __restrict__ be1,
                 const float* __restrict__ W2T, const float* __restrict__ S2T,
                 const float* __restrict__ b2, const float* __restrict__ eta2p,
                 const float* __restrict__ g2, const float* __restrict__ be2,
                 const float* __restrict__ hw, const float* __restrict__ hbod,
                 float* __restrict__ out)
{
    __shared__ float sh[2][256];
    __shared__ float sc[2][256];
    __shared__ float sv[2][128];
    __shared__ float sh2[2][128];
    __shared__ float sc2[2][128];
    __shared__ float sv2[2][64];
    __shared__ float p2a[2][2][64];  // [dhalf][row][h2]
    __shared__ float p2b[2][2][64];
    __shared__ float redA[4][2];     // [wave][row]
    __shared__ float redB[4][2];

    const int t = threadIdx.x;       // column 0..255
    const int b0 = blockIdx.x * 2;
    const int lane = t & 63;
    const int wv = t >> 6;

    // ---- combine phase: split-K reduce + plastic for 2 rows ----
    // s-outer / r-inner with unroll(4): 16 independent loads in flight per group
    const float e0 = eta0p[0];
    const float bias0 = b0v[t];
    float ys[2] = {0.f, 0.f}, ps[2] = {0.f, 0.f};
    #pragma unroll 4
    for (int s = 0; s < 16; ++s)
        #pragma unroll
        for (int r = 0; r < 2; ++r) {
            size_t o = ((size_t)s * 1024 + b0 + r) * 256 + t;
            ys[r] += Py[o];
            ps[r] += Pp[o];
        }
    float v[2];
    #pragma unroll
    for (int r = 0; r < 2; ++r) {
        float p = ps[r] * hnorm[b0 + r];
        float y = ys[r] + bias0;
        v[r] = y + e0 * tanhf(y) * p;
    }

    // LN(256) over columns, both rows in one barrier round
    float s1[2], s2[2];
    #pragma unroll
    for (int r = 0; r < 2; ++r) { s1[r] = v[r]; s2[r] = v[r] * v[r]; }
    #pragma unroll
    for (int o = 32; o; o >>= 1)
        #pragma unroll
        for (int r = 0; r < 2; ++r) { s1[r] += __shfl_xor(s1[r], o); s2[r] += __shfl_xor(s2[r], o); }
    if (lane == 0)
        #pragma unroll
        for (int r = 0; r < 2; ++r) { redA[wv][r] = s1[r]; redB[wv][r] = s2[r]; }
    __syncthreads();

    const float gg = g0[t], bb = be0[t];
    float gl[2], s3[2];
    #pragma unroll
    for (int r = 0; r < 2; ++r) {
        float sum = redA[0][r] + redA[1][r] + redA[2][r] + redA[3][r];
        float sumsq = redB[0][r] + redB[1][r] + redB[2][r] + redB[3][r];
        float mu = sum * (1.f / 256.f);
        float var = sumsq * (1.f / 256.f) - mu * mu;
        float u = (v[r] - mu) * rsqrtf(var + 1e-5f) * gg + bb;
        gl[r] = gelu_f(u);
        s3[r] = gl[r] * gl[r];
    }
    #pragma unroll
    for (int o = 32; o; o >>= 1)
        #pragma unroll
        for (int r = 0; r < 2; ++r) s3[r] += __shfl_xor(s3[r], o);
    __syncthreads();                 // redA reuse guard
    if (lane == 0)
        #pragma unroll
        for (int r = 0; r < 2; ++r) redA[wv][r] = s3[r];
    __syncthreads();
    #pragma unroll
    for (int r = 0; r < 2; ++r) {
        float gsq = redA[0][r] + redA[1][r] + redA[2][r] + redA[3][r];
        float inv = 1.f / (sqrtf(gsq) + 1e-8f);
        sh[r][t] = gl[r];
        sc[r][t] = gl[r] * gl[r] * inv;
    }
    __syncthreads();

    // ---- layer 1: 128 outputs x 2 rows; one (row, col) per thread ----
    const int hcol = t & 127;
    const int r1 = t >> 7;           // 0..1
    float ya = 0.f, pa = 0.f;
    #pragma unroll 8
    for (int d = 0; d < 256; ++d) {
        ya += sh[r1][d] * W1T[d * 128 + hcol];
        pa += sc[r1][d] * S1T[d * 128 + hcol];
    }
    {
        const float e1 = eta1p[0];
        float y = ya + b1[hcol];
        sv[r1][hcol] = y + e1 * tanhf(y) * pa;
    }
    __syncthreads();

    // LN(128) + gelu + c2: wave per row (waves 0,1)
    if (wv < 2) {
        int r = wv;
        float v0 = sv[r][lane];
        float v1 = sv[r][lane + 64];
        float s = v0 + v1, sq = v0 * v0 + v1 * v1;
        #pragma unroll
        for (int o = 32; o; o >>= 1) { s += __shfl_xor(s, o); sq += __shfl_xor(sq, o); }
        float mu = s * (1.f / 128.f);
        float var = sq * (1.f / 128.f) - mu * mu;
        float rs = rsqrtf(var + 1e-5f);
        float u0 = (v0 - mu) * rs * g1[lane] + be1[lane];
        float u1 = (v1 - mu) * rs * g1[lane + 64] + be1[lane + 64];
        float ge0 = gelu_f(u0);
        float ge1 = gelu_f(u1);
        float gsq = ge0 * ge0 + ge1 * ge1;
        #pragma unroll
        for (int o = 32; o; o >>= 1) gsq += __shfl_xor(gsq, o);
        float inv = 1.f / (sqrtf(gsq) + 1e-8f);
        sh2[r][lane] = ge0; sh2[r][lane + 64] = ge1;
        sc2[r][lane] = ge0 * ge0 * inv; sc2[r][lane + 64] = ge1 * ge1 * inv;
    }
    __syncthreads();

    // ---- layer 2: 64 outputs x 2 rows, d-dim split across 2 halves so all
    // 4 waves stay busy in the serial dot loops; LDS combine after ----
    {
        const int h2c = t & 63;
        const int r = (t >> 6) & 1;
        const int dh = t >> 7;       // 0..1
        float yb = 0.f, pb = 0.f;
        #pragma unroll 8
        for (int dd = 0; dd < 64; ++dd) {
            int d = dh * 64 + dd;
            yb += sh2[r][d] * W2T[d * 64 + h2c];
            pb += sc2[r][d] * S2T[d * 64 + h2c];
        }
        p2a[dh][r][h2c] = yb;
        p2b[dh][r][h2c] = pb;
    }
    __syncthreads();
    if (t < 128) {
        const int h2c = t & 63;
        const int r = t >> 6;
        const float e2 = eta2p[0];
        float yb = p2a[0][r][h2c] + p2a[1][r][h2c];
        float pb = p2b[0][r][h2c] + p2b[1][r][h2c];
        float y = yb + b2[h2c];
        sv2[r][h2c] = y + e2 * tanhf(y) * pb;
    }
    __syncthreads();

    // LN(64) + gelu + head: wave per row (waves 0,1)
    if (wv < 2) {
        int r = wv;
        float v0 = sv2[r][lane];
        float s = v0, sq = v0 * v0;
        #pragma unroll
        for (int o = 32; o; o >>= 1) { s += __shfl_xor(s, o); sq += __shfl_xor(sq, o); }
        float mu = s * (1.f / 64.f);
        float var = sq * (1.f / 64.f) - mu * mu;
        float rs = rsqrtf(var + 1e-5f);
        float u = (v0 - mu) * rs * g2[lane] + be2[lane];
        float g = gelu_f(u);
        float hc = g * hw[lane];
        #pragma unroll
        for (int o = 32; o; o >>= 1) hc += __shfl_xor(hc, o);
        if (lane == 0) out[b0 + r] = hc + hbod[0];
    }
}

// ---------------------------------------------------------------------------
extern "C" void kernel_launch(void* const* d_in, const int* in_sizes, int n_in,
                              void* d_out, int out_size, void* d_ws, size_t ws_size,
                              hipStream_t stream)
{
    const float* x    = (const float*)d_in[0];
    const float* W0   = (const float*)d_in[1];
    const float* A0   = (const float*)d_in[2];
    const float* b0   = (const float*)d_in[3];
    const float* eta0 = (const float*)d_in[4];
    const float* g0   = (const float*)d_in[5];
    const float* be0  = (const float*)d_in[6];
    const float* W1   = (const float*)d_in[7];
    const float* A1   = (const float*)d_in[8];
    const float* b1   = (const float*)d_in[9];
    const float* eta1 = (const float*)d_in[10];
    const float* g1   = (const float*)d_in[11];
    const float* be1  = (const float*)d_in[12];
    const float* W2   = (const float*)d_in[13];
    const float* A2   = (const float*)d_in[14];
    const float* b2   = (const float*)d_in[15];
    const float* eta2 = (const float*)d_in[16];
    const float* g2   = (const float*)d_in[17];
    const float* be2  = (const float*)d_in[18];
    const float* hw   = (const float*)d_in[19];
    const float* hbod = (const float*)d_in[20];
    float* out = (float*)d_out;

    char* w = (char*)d_ws;
    unsigned short* hb  = (unsigned short*)(w + 0);          // 20971520
    unsigned short* Wb0 = (unsigned short*)(w + 20971520);   // 5242880
    unsigned short* Sb0 = (unsigned short*)(w + 26214400);   // 5242880
    float* Py   = (float*)(w + 31457280);                    // 16777216
    float* Pp   = (float*)(w + 48234496);                    // 16777216
    float* W1T  = (float*)(w + 65011712);                    // 131072
    float* S1T  = (float*)(w + 65142784);                    // 131072
    float* W2T  = (float*)(w + 65273856);                    // 32768
    float* S2T  = (float*)(w + 65306624);                    // 32768
    float* hnm  = (float*)(w + 65339392);                    // 4096
    unsigned int* idxT = (unsigned int*)(w + 65343488);      // 40960 (10001 u32)
    float2* twT = (float2*)(w + 65384448);                   // 71936 (8992 float2)
    // total = 65456384 bytes

    hipLaunchKernelGGL(init_tables_kernel, dim3(40), dim3(256), 0, stream, idxT, twT);
    hipLaunchKernelGGL(fft_prep_kernel, dim3(3804), dim3(512), 0, stream,
                       x, hb, hnm, W0, A0, Wb0, Sb0, W1, A1, W2, A2, W1T, S1T, W2T, S2T,
                       idxT, twT);
    hipLaunchKernelGGL(gemm0_kernel, dim3(512), dim3(256), 0, stream, hb, Wb0, Sb0, Py, Pp);
    hipLaunchKernelGGL(combine_tail_kernel, dim3(512), dim3(256), 0, stream, Py, Pp, hnm,
                       b0, eta0, g0, be0, W1T, S1T, b1, eta1, g1, be1,
                       W2T, S2T, b2, eta2, g2, be2, hw, hbod, out);
}

// Round 2
// 251.895 us; speedup vs baseline: 1.0552x; 1.0552x over previous
//
#include <hip/hip_runtime.h>
#include <hip/hip_bf16.h>
#include <math.h>

typedef short bf16x8 __attribute__((ext_vector_type(8)));
typedef float f32x4 __attribute__((ext_vector_type(4)));

static __device__ __forceinline__ unsigned short f2bf(float f) {
    unsigned int u = __float_as_uint(f);
    unsigned int r = (u + 0x7fffu + ((u >> 16) & 1u)) >> 16;
    return (unsigned short)r;
}

// elementwise square of a bf16x8 fragment (bf16 -> f32 -> square -> bf16 rne)
static __device__ __forceinline__ bf16x8 sq_bf16x8(bf16x8 a) {
    bf16x8 r;
    #pragma unroll
    for (int i = 0; i < 8; ++i) {
        unsigned int u = ((unsigned int)(unsigned short)a[i]) << 16;
        float f = __uint_as_float(u);
        f *= f;
        r[i] = (short)f2bf(f);
    }
    return r;
}

static __device__ __forceinline__ float gelu_f(float x) {
    return 0.5f * x * (1.f + erff(x * 0.70710678118654752f));
}

// async global->LDS, 16B per lane; LDS dest is wave-uniform base + lane*16
static __device__ __forceinline__ void gload_lds16(const void* g, void* l) {
    __builtin_amdgcn_global_load_lds(
        (const __attribute__((address_space(1))) unsigned int*)g,
        (__attribute__((address_space(3))) unsigned int*)l, 16, 0, 0);
}

// LDS index skew for FFT buffers
static __device__ __forceinline__ int ldsmap(int i) { return i + (i >> 6); }

static __device__ __forceinline__ int rev4(int k) {
    int d0 = k % 10; k /= 10;
    int d1 = k % 10; k /= 10;
    int d2 = k % 10; int d3 = k / 10;
    return d0 * 1000 + d1 * 100 + d2 * 10 + d3;
}

// ---------------------------------------------------------------------------
// Per-launch constant table (workspace is re-poisoned each run):
//  idxTab[k] (k in 0..10000): packed u16 pair (ldsmap(rev4(k1)), ldsmap(rev4(k2)))
// Read COALESCED in the untangle (k = tid + i*512 -> consecutive lanes,
// consecutive words, L1-resident 40KB). NOTE round-1 lesson: the butterfly
// twiddle table regressed -13% because its per-lane index j*SC*t is SCATTERED
// (up to 64 cache lines per wave-load); butterflies keep in-register sincos.
// ---------------------------------------------------------------------------
__global__ __launch_bounds__(256)
void init_tables_kernel(unsigned int* __restrict__ idxTab)
{
    int i = blockIdx.x * 256 + threadIdx.x;
    if (i < 10001) {
        int k1 = (i == 10000) ? 0 : i;
        int k2 = (k1 == 0) ? 0 : 10000 - k1;
        unsigned a = (unsigned)ldsmap(rev4(k1));
        unsigned b = (unsigned)ldsmap(rev4(k2));
        idxTab[i] = a | (b << 16);
    }
}

// forward 5-point DFT (W5 = e^{-2pi i/5}), Winograd-style
static __device__ __forceinline__ void dft5(
    float a0r, float a0i, float a1r, float a1i, float a2r, float a2i,
    float a3r, float a3i, float a4r, float a4i,
    float* Xr, float* Xi)
{
    const float c1 = 0.30901699437494742f, c2 = -0.80901699437494745f;
    const float s1 = 0.95105651629515357f, s2 = 0.58778525229247312f;
    float t1r = a1r + a4r, t1i = a1i + a4i;
    float d1r = a1r - a4r, d1i = a1i - a4i;
    float t2r = a2r + a3r, t2i = a2i + a3i;
    float d2r = a2r - a3r, d2i = a2i - a3i;
    Xr[0] = a0r + t1r + t2r; Xi[0] = a0i + t1i + t2i;
    float m1r = a0r + c1 * t1r + c2 * t2r, m1i = a0i + c1 * t1i + c2 * t2i;
    float m2r = a0r + c2 * t1r + c1 * t2r, m2i = a0i + c2 * t1i + c1 * t2i;
    float n1r = s1 * d1r + s2 * d2r, n1i = s1 * d1i + s2 * d2i;
    float n2r = s2 * d1r - s1 * d2r, n2i = s2 * d1i - s1 * d2i;
    Xr[1] = m1r + n1i; Xi[1] = m1i - n1r;
    Xr[4] = m1r - n1i; Xi[4] = m1i + n1r;
    Xr[2] = m2r + n2i; Xi[2] = m2i - n2r;
    Xr[3] = m2r - n2i; Xi[3] = m2i + n2r;
}

// core of a radix-10 DIF butterfly given 10 loaded taps; writes LDS (twiddled)
// twiddles computed IN-REGISTER (sincos + recurrence) -- see round-1 note.
template<int S>
static __device__ __forceinline__ void radix10_core(
    float* __restrict__ reb, float* __restrict__ imb,
    const float* ar, const float* ai, int base, int j)
{
    constexpr int L  = (S == 0) ? 1000 : (S == 1) ? 100 : (S == 2) ? 10 : 1;
    constexpr int SC = (S == 0) ? 1 : (S == 1) ? 10 : (S == 2) ? 100 : 1000;
    constexpr bool TW = (S != 3);

    const float WR[5] = {1.f, 0.80901699437494745f, 0.30901699437494742f,
                         -0.30901699437494742f, -0.80901699437494745f};
    const float WI[5] = {0.f, -0.58778525229247312f, -0.95105651629515357f,
                         -0.95105651629515357f, -0.58778525229247312f};

    float Er[5], Ei[5], Or[5], Oi[5];
    dft5(ar[0], ai[0], ar[2], ai[2], ar[4], ai[4], ar[6], ai[6], ar[8], ai[8], Er, Ei);
    dft5(ar[1], ai[1], ar[3], ai[3], ar[5], ai[5], ar[7], ai[7], ar[9], ai[9], Or, Oi);
    #pragma unroll
    for (int k = 1; k < 5; ++k) {
        float tr = Or[k] * WR[k] - Oi[k] * WI[k];
        Oi[k] = Or[k] * WI[k] + Oi[k] * WR[k];
        Or[k] = tr;
    }

    if (TW) {
        const float ang = (float)(j * SC) * -6.28318530717958648e-4f;
        float w1c, w1s;
        __sincosf(ang, &w1s, &w1c);
        float twr[10], twi[10];
        twr[0] = 1.f; twi[0] = 0.f;
        #pragma unroll
        for (int t = 1; t < 10; ++t) {
            twr[t] = twr[t - 1] * w1c - twi[t - 1] * w1s;
            twi[t] = twr[t - 1] * w1s + twi[t - 1] * w1c;
        }
        #pragma unroll
        for (int k = 0; k < 5; ++k) {
            float xr0 = Er[k] + Or[k], xi0 = Ei[k] + Oi[k];
            float xr1 = Er[k] - Or[k], xi1 = Ei[k] - Oi[k];
            int i0 = ldsmap(base + k * L);
            int i1 = ldsmap(base + (k + 5) * L);
            if (k == 0) {
                reb[i0] = xr0;
                imb[i0] = xi0;
            } else {
                reb[i0] = xr0 * twr[k] - xi0 * twi[k];
                imb[i0] = xr0 * twi[k] + xi0 * twr[k];
            }
            reb[i1] = xr1 * twr[k + 5] - xi1 * twi[k + 5];
            imb[i1] = xr1 * twi[k + 5] + xi1 * twr[k + 5];
        }
    } else {
        #pragma unroll
        for (int k = 0; k < 5; ++k) {
            int i0 = ldsmap(base + k * L);
            int i1 = ldsmap(base + (k + 5) * L);
            reb[i0] = Er[k] + Or[k]; imb[i0] = Ei[k] + Oi[k];
            reb[i1] = Er[k] - Or[k]; imb[i1] = Ei[k] - Oi[k];
        }
    }
}

// radix-10 DIF stage for S>=1 (reads LDS)
template<int S>
static __device__ __forceinline__ void radix10_stage(
    float* __restrict__ reb, float* __restrict__ imb, int tid)
{
    constexpr int L = (S == 1) ? 100 : (S == 2) ? 10 : 1;
    for (int w = tid; w < 1000; w += 512) {
        int g, j;
        if (S == 3) { g = w; j = 0; }
        else        { g = w / L; j = w - g * L; }
        const int base = g * (10 * L) + j;
        float ar[10], ai[10];
        #pragma unroll
        for (int u = 0; u < 10; ++u) {
            int idx = ldsmap(base + u * L);
            ar[u] = reb[idx];
            ai[u] = imb[idx];
        }
        radix10_core<S>(reb, imb, ar, ai, base, j);
    }
}

// ---------------------------------------------------------------------------
// Fused FFT + prep. Blocks [0,1024): FFT rows (512 thr, 1 row/block, 81 KB
// LDS, 2 blocks/CU). Mean-subtraction eliminated algebraically (affects only
// bin 0, where centered X[0]=0 exactly -> h[0]=0 forced). Stage 0 fused with
// the global load. Untangle: coalesced idxTab lookup (kills rev4 div-chains)
// + per-thread rotor recurrence (kills per-bin sincos).
// Blocks [1024,3804): weight prep.
// ---------------------------------------------------------------------------
__global__ __launch_bounds__(512, 4)
void fft_prep_kernel(const float* __restrict__ x,
                     unsigned short* __restrict__ hb,
                     float* __restrict__ hnorm,
                     const float* __restrict__ W0, const float* __restrict__ A0,
                     unsigned short* __restrict__ Wb, unsigned short* __restrict__ Sb,
                     const float* __restrict__ W1, const float* __restrict__ A1,
                     const float* __restrict__ W2, const float* __restrict__ A2,
                     float* __restrict__ W1T, float* __restrict__ S1T,
                     float* __restrict__ W2T, float* __restrict__ S2T,
                     const unsigned int* __restrict__ idxTab)
{
    if (blockIdx.x >= 1024) {
        // ---- prep path ----
        int idx = (blockIdx.x - 1024) * 512 + threadIdx.x;
        if (idx < 1280128) {
            const bool isW = idx < 640064;
            const int f4 = isW ? idx : idx - 640064;
            const float* src = isW ? W0 : A0;
            unsigned short* dst = isW ? Wb : Sb;
            float4 v = ((const float4*)src)[f4];
            float e[4] = {v.x, v.y, v.z, v.w};
            int flat = f4 * 4;
            int row = flat / 10001;
            int col = flat - row * 10001;
            #pragma unroll
            for (int i = 0; i < 4; ++i) {
                if (col == 10001) { row++; col = 0; }
                float val = isW ? e[i] : 1.f / (1.f + expf(-e[i]));
                dst[(size_t)row * 10240 + col] = f2bf(val);
                col++;
            }
        } else if (idx < 1341312) {
            int i = idx - 1280128;              // 256*239 pads
            int row = i / 239;
            int col = 10001 + (i - row * 239);
            Wb[(size_t)row * 10240 + col] = 0;
            Sb[(size_t)row * 10240 + col] = 0;
        } else if (idx < 1423232) {
            int o = idx - 1341312;              // 0..81919
            if (o < 32768) {
                int d = o >> 7, h = o & 127;
                W1T[o] = W1[h * 256 + d];
            } else if (o < 65536) {
                int p = o - 32768;
                int d = p >> 7, h = p & 127;
                S1T[p] = 1.f / (1.f + expf(-A1[h * 256 + d]));
            } else if (o < 73728) {
                int p = o - 65536;
                int d = p >> 6, h = p & 63;
                W2T[p] = W2[h * 128 + d];
            } else {
                int p = o - 73728;
                int d = p >> 6, h = p & 63;
                S2T[p] = 1.f / (1.f + expf(-A2[h * 128 + d]));
            }
        }
        return;
    }

    // ---- FFT path ----
    __shared__ float reb[10156];
    __shared__ float imb[10156];
    __shared__ float redbuf[8];

    const int b = blockIdx.x;
    const int tid = threadIdx.x;
    const int lane = tid & 63;
    const int wv = tid >> 6;

    // stage 0 fused with global load: z[n] = (x[2n], x[2n+1]) as float2
    const float2* z2 = (const float2*)(x + (size_t)b * 20000);
    for (int w = tid; w < 1000; w += 512) {
        float ar[10], ai[10];
        #pragma unroll
        for (int u = 0; u < 10; ++u) {
            float2 v = z2[w + u * 1000];
            ar[u] = v.x; ai[u] = v.y;
        }
        radix10_core<0>(reb, imb, ar, ai, w, w);
    }
    __syncthreads();
    radix10_stage<1>(reb, imb, tid);
    __syncthreads();
    radix10_stage<2>(reb, imb, tid);
    __syncthreads();
    radix10_stage<3>(reb, imb, tid);
    __syncthreads();

    // real-FFT untangle + log(1+|X|); h[0]=0 exactly (centered DC bin).
    // (ct,st) = exp(-i*pi*k/10000) advanced by a constant rotor per i-step
    // (k += 512): cos/sin(-512*pi/10000) = (0.987091579, -0.160156842).
    float ct, st;
    __sincosf((float)tid * -3.14159265358979324e-4f, &st, &ct);
    const float RC = 0.987091579f;
    const float RS = -0.160156842f;
    float sumsq = 0.f;
    unsigned short* hrow = hb + (size_t)b * 10240;
    #pragma unroll
    for (int i = 0; i < 20; ++i) {
        int k = tid + i * 512;
        float hval = 0.f;
        if (k > 0 && k <= 10000) {
            unsigned pp = idxTab[k];
            int i1 = (int)(pp & 0xffffu);
            int i2 = (int)(pp >> 16);
            float zr = reb[i1], zi = imb[i1];
            float wr = reb[i2], wi = imb[i2];
            float er = 0.5f * (zr + wr);
            float ei = 0.5f * (zi - wi);
            float odr = 0.5f * (zi + wi);
            float odi = -0.5f * (zr - wr);
            float xre = er + ct * odr - st * odi;
            float xim = ei + ct * odi + st * odr;
            hval = __logf(1.f + sqrtf(xre * xre + xim * xim));
        }
        hrow[k] = f2bf(hval);
        sumsq += hval * hval;
        // advance rotor (use old ct for both products)
        float nct = ct * RC - st * RS;
        st = ct * RS + st * RC;
        ct = nct;
    }
    #pragma unroll
    for (int o = 32; o; o >>= 1) sumsq += __shfl_xor(sumsq, o);
    __syncthreads();
    if (lane == 0) redbuf[wv] = sumsq;
    __syncthreads();
    if (tid == 0) {
        float tsq = 0.f;
        #pragma unroll
        for (int i = 0; i < 8; ++i) tsq += redbuf[i];
        hnorm[b] = 1.f / (sqrtf(tsq) + 1e-8f);
    }
}

// ---------------------------------------------------------------------------
// Layer-0 dual GEMM: Y = h*W0^T, P = (h^2)*S0^T (1/||h|| applied downstream).
// BM=128 BN=64 BK=64, split-K=16. Linear grid 512 with XCD-aware decode:
// XCD c (= lin%8, round-robin dispatch) owns k-slices z in {2c, 2c+1}, so the
// per-XCD live operand footprint (2*1.25MB A-slices + 1.25MB B-slices) fits
// the 4MB per-XCD L2 -> A/B re-reads become L2 hits instead of HBM refetch.
// 3 blocks/CU (acc+frags ~150 VGPR < 170 cap) to cover vmcnt(0) barrier drains.
// ---------------------------------------------------------------------------
__global__ __launch_bounds__(256, 3)
void gemm0_kernel(const unsigned short* __restrict__ hb,
                  const unsigned short* __restrict__ Wb, const unsigned short* __restrict__ Sb,
                  float* __restrict__ Py, float* __restrict__ Pp)
{
    __shared__ unsigned short Ah[128 * 64];
    __shared__ unsigned short Bw[64 * 64];
    __shared__ unsigned short Bs[64 * 64];

    const int t = threadIdx.x;
    // bijective decode: lin -> (xcd, z, m-tile, n-tile)
    const int lin = blockIdx.x;           // 0..511
    const int xcd = lin & 7;
    const int sub = lin >> 3;             // 0..63
    const int z = xcd * 2 + (sub & 1);    // 0..15, z-pair per XCD
    const int tile = sub >> 1;            // 0..31
    const int b0 = (tile & 7) * 128;
    const int n0 = (tile >> 3) * 64;

    const int lane = t & 63;
    const int wv = t >> 6;
    const int ml = lane & 15;
    const int q4 = lane >> 4;
    const int s0 = q4 ^ (ml & 7);

    const int sub8 = lane >> 3;
    const int sl = lane & 7;
    const int gsw = sl ^ sub8;

    f32x4 accY[2][4], accP[2][4];
    #pragma unroll
    for (int mt = 0; mt < 2; ++mt)
        #pragma unroll
        for (int nt = 0; nt < 4; ++nt) {
            accY[mt][nt] = (f32x4){0.f, 0.f, 0.f, 0.f};
            accP[mt][nt] = (f32x4){0.f, 0.f, 0.f, 0.f};
        }

    const int kbase = z * 640;

    for (int step = 0; step < 10; ++step) {
        const int k0 = kbase + step * 64;
        __syncthreads();
        #pragma unroll
        for (int j = 0; j < 4; ++j) {
            const int c = wv * 4 + j;
            const size_t go = (size_t)(b0 + c * 8 + sub8) * 10240 + k0 + gsw * 8;
            gload_lds16(&hb[go], &Ah[c * 512]);
        }
        #pragma unroll
        for (int j = 0; j < 2; ++j) {
            const int c = wv * 2 + j;
            const size_t go = (size_t)(n0 + c * 8 + sub8) * 10240 + k0 + gsw * 8;
            gload_lds16(&Wb[go], &Bw[c * 512]);
            gload_lds16(&Sb[go], &Bs[c * 512]);
        }
        __syncthreads();

        #pragma unroll
        for (int kk = 0; kk < 2; ++kk) {
            const int slot = (s0 ^ (kk << 2)) << 3;
            bf16x8 ah[2], ac[2], bw[4], bs[4];
            #pragma unroll
            for (int mt = 0; mt < 2; ++mt) {
                int mrow = wv * 32 + mt * 16 + ml;
                ah[mt] = *(const bf16x8*)&Ah[mrow * 64 + slot];
                ac[mt] = sq_bf16x8(ah[mt]);
            }
            #pragma unroll
            for (int nt = 0; nt < 4; ++nt) {
                int nrow = nt * 16 + ml;
                bw[nt] = *(const bf16x8*)&Bw[nrow * 64 + slot];
                bs[nt] = *(const bf16x8*)&Bs[nrow * 64 + slot];
            }
            #pragma unroll
            for (int mt = 0; mt < 2; ++mt)
                #pragma unroll
                for (int nt = 0; nt < 4; ++nt) {
                    accY[mt][nt] = __builtin_amdgcn_mfma_f32_16x16x32_bf16(ah[mt], bw[nt], accY[mt][nt], 0, 0, 0);
                    accP[mt][nt] = __builtin_amdgcn_mfma_f32_16x16x32_bf16(ac[mt], bs[nt], accP[mt][nt], 0, 0, 0);
                }
        }
    }

    const int rq = q4 * 4;
    #pragma unroll
    for (int mt = 0; mt < 2; ++mt)
        #pragma unroll
        for (int nt = 0; nt < 4; ++nt)
            #pragma unroll
            for (int r = 0; r < 4; ++r) {
                int m = b0 + wv * 32 + mt * 16 + rq + r;
                int n = n0 + nt * 16 + ml;
                size_t o = ((size_t)z * 1024 + m) * 256 + n;
                Py[o] = accY[mt][nt][r];
                Pp[o] = accP[mt][nt][r];
            }
}

// ---------------------------------------------------------------------------
// Fused combine + tail: split-K reduce + layer-0 plastic/LN/GELU (in LDS),
// then layers 1,2 + head. 2 rows per block, grid 512 x 256 thr
// (2 blocks/CU = 2 waves/SIMD; layer-2's d-loop split across all 4 waves).
// ---------------------------------------------------------------------------
__global__ __launch_bounds__(256)
void combine_tail_kernel(const float* __restrict__ Py, const float* __restrict__ Pp,
                 const float* __restrict__ hnorm,
                 const float* __restrict__ b0v, const float* __restrict__ eta0p,
                 const float* __restrict__ g0, const float* __restrict__ be0,
                 const float* __restrict__ W1T, const float* __restrict__ S1T,
                 const float* __restrict__ b1, const float* __restrict__ eta1p,
                 const float* __restrict__ g1, const float* __restrict__ be1,
                 const float* __restrict__ W2T, const float* __restrict__ S2T,
                 const float* __restrict__ b2, const float* __restrict__ eta2p,
                 const float* __restrict__ g2, const float* __restrict__ be2,
                 const float* __restrict__ hw, const float* __restrict__ hbod,
                 float* __restrict__ out)
{
    __shared__ float sh[2][256];
    __shared__ float sc[2][256];
    __shared__ float sv[2][128];
    __shared__ float sh2[2][128];
    __shared__ float sc2[2][128];
    __shared__ float sv2[2][64];
    __shared__ float p2a[2][2][64];  // [dhalf][row][h2]
    __shared__ float p2b[2][2][64];
    __shared__ float redA[4][2];     // [wave][row]
    __shared__ float redB[4][2];

    const int t = threadIdx.x;       // column 0..255
    const int b0 = blockIdx.x * 2;
    const int lane = t & 63;
    const int wv = t >> 6;

    // ---- combine phase: split-K reduce + plastic for 2 rows ----
    const float e0 = eta0p[0];
    const float bias0 = b0v[t];
    float ys[2] = {0.f, 0.f}, ps[2] = {0.f, 0.f};
    #pragma unroll 4
    for (int s = 0; s < 16; ++s)
        #pragma unroll
        for (int r = 0; r < 2; ++r) {
            size_t o = ((size_t)s * 1024 + b0 + r) * 256 + t;
            ys[r] += Py[o];
            ps[r] += Pp[o];
        }
    float v[2];
    #pragma unroll
    for (int r = 0; r < 2; ++r) {
        float p = ps[r] * hnorm[b0 + r];
        float y = ys[r] + bias0;
        v[r] = y + e0 * tanhf(y) * p;
    }

    // LN(256) over columns, both rows in one barrier round
    float s1[2], s2[2];
    #pragma unroll
    for (int r = 0; r < 2; ++r) { s1[r] = v[r]; s2[r] = v[r] * v[r]; }
    #pragma unroll
    for (int o = 32; o; o >>= 1)
        #pragma unroll
        for (int r = 0; r < 2; ++r) { s1[r] += __shfl_xor(s1[r], o); s2[r] += __shfl_xor(s2[r], o); }
    if (lane == 0)
        #pragma unroll
        for (int r = 0; r < 2; ++r) { redA[wv][r] = s1[r]; redB[wv][r] = s2[r]; }
    __syncthreads();

    const float gg = g0[t], bb = be0[t];
    float gl[2], s3[2];
    #pragma unroll
    for (int r = 0; r < 2; ++r) {
        float sum = redA[0][r] + redA[1][r] + redA[2][r] + redA[3][r];
        float sumsq = redB[0][r] + redB[1][r] + redB[2][r] + redB[3][r];
        float mu = sum * (1.f / 256.f);
        float var = sumsq * (1.f / 256.f) - mu * mu;
        float u = (v[r] - mu) * rsqrtf(var + 1e-5f) * gg + bb;
        gl[r] = gelu_f(u);
        s3[r] = gl[r] * gl[r];
    }
    #pragma unroll
    for (int o = 32; o; o >>= 1)
        #pragma unroll
        for (int r = 0; r < 2; ++r) s3[r] += __shfl_xor(s3[r], o);
    __syncthreads();                 // redA reuse guard
    if (lane == 0)
        #pragma unroll
        for (int r = 0; r < 2; ++r) redA[wv][r] = s3[r];
    __syncthreads();
    #pragma unroll
    for (int r = 0; r < 2; ++r) {
        float gsq = redA[0][r] + redA[1][r] + redA[2][r] + redA[3][r];
        float inv = 1.f / (sqrtf(gsq) + 1e-8f);
        sh[r][t] = gl[r];
        sc[r][t] = gl[r] * gl[r] * inv;
    }
    __syncthreads();

    // ---- layer 1: 128 outputs x 2 rows; one (row, col) per thread ----
    const int hcol = t & 127;
    const int r1 = t >> 7;           // 0..1
    float ya = 0.f, pa = 0.f;
    #pragma unroll 8
    for (int d = 0; d < 256; ++d) {
        ya += sh[r1][d] * W1T[d * 128 + hcol];
        pa += sc[r1][d] * S1T[d * 128 + hcol];
    }
    {
        const float e1 = eta1p[0];
        float y = ya + b1[hcol];
        sv[r1][hcol] = y + e1 * tanhf(y) * pa;
    }
    __syncthreads();

    // LN(128) + gelu + c2: wave per row (waves 0,1)
    if (wv < 2) {
        int r = wv;
        float v0 = sv[r][lane];
        float v1 = sv[r][lane + 64];
        float s = v0 + v1, sq = v0 * v0 + v1 * v1;
        #pragma unroll
        for (int o = 32; o; o >>= 1) { s += __shfl_xor(s, o); sq += __shfl_xor(sq, o); }
        float mu = s * (1.f / 128.f);
        float var = sq * (1.f / 128.f) - mu * mu;
        float rs = rsqrtf(var + 1e-5f);
        float u0 = (v0 - mu) * rs * g1[lane] + be1[lane];
        float u1 = (v1 - mu) * rs * g1[lane + 64] + be1[lane + 64];
        float ge0 = gelu_f(u0);
        float ge1 = gelu_f(u1);
        float gsq = ge0 * ge0 + ge1 * ge1;
        #pragma unroll
        for (int o = 32; o; o >>= 1) gsq += __shfl_xor(gsq, o);
        float inv = 1.f / (sqrtf(gsq) + 1e-8f);
        sh2[r][lane] = ge0; sh2[r][lane + 64] = ge1;
        sc2[r][lane] = ge0 * ge0 * inv; sc2[r][lane + 64] = ge1 * ge1 * inv;
    }
    __syncthreads();

    // ---- layer 2: 64 outputs x 2 rows, d-dim split across 2 halves so all
    // 4 waves stay busy in the serial dot loops; LDS combine after ----
    {
        const int h2c = t & 63;
        const int r = (t >> 6) & 1;
        const int dh = t >> 7;       // 0..1
        float yb = 0.f, pb = 0.f;
        #pragma unroll 8
        for (int dd = 0; dd < 64; ++dd) {
            int d = dh * 64 + dd;
            yb += sh2[r][d] * W2T[d * 64 + h2c];
            pb += sc2[r][d] * S2T[d * 64 + h2c];
        }
        p2a[dh][r][h2c] = yb;
        p2b[dh][r][h2c] = pb;
    }
    __syncthreads();
    if (t < 128) {
        const int h2c = t & 63;
        const int r = t >> 6;
        const float e2 = eta2p[0];
        float yb = p2a[0][r][h2c] + p2a[1][r][h2c];
        float pb = p2b[0][r][h2c] + p2b[1][r][h2c];
        float y = yb + b2[h2c];
        sv2[r][h2c] = y + e2 * tanhf(y) * pb;
    }
    __syncthreads();

    // LN(64) + gelu + head: wave per row (waves 0,1)
    if (wv < 2) {
        int r = wv;
        float v0 = sv2[r][lane];
        float s = v0, sq = v0 * v0;
        #pragma unroll
        for (int o = 32; o; o >>= 1) { s += __shfl_xor(s, o); sq += __shfl_xor(sq, o); }
        float mu = s * (1.f / 64.f);
        float var = sq * (1.f / 64.f) - mu * mu;
        float rs = rsqrtf(var + 1e-5f);
        float u = (v0 - mu) * rs * g2[lane] + be2[lane];
        float g = gelu_f(u);
        float hc = g * hw[lane];
        #pragma unroll
        for (int o = 32; o; o >>= 1) hc += __shfl_xor(hc, o);
        if (lane == 0) out[b0 + r] = hc + hbod[0];
    }
}

// ---------------------------------------------------------------------------
extern "C" void kernel_launch(void* const* d_in, const int* in_sizes, int n_in,
                              void* d_out, int out_size, void* d_ws, size_t ws_size,
                              hipStream_t stream)
{
    const float* x    = (const float*)d_in[0];
    const float* W0   = (const float*)d_in[1];
    const float* A0   = (const float*)d_in[2];
    const float* b0   = (const float*)d_in[3];
    const float* eta0 = (const float*)d_in[4];
    const float* g0   = (const float*)d_in[5];
    const float* be0  = (const float*)d_in[6];
    const float* W1   = (const float*)d_in[7];
    const float* A1   = (const float*)d_in[8];
    const float* b1   = (const float*)d_in[9];
    const float* eta1 = (const float*)d_in[10];
    const float* g1   = (const float*)d_in[11];
    const float* be1  = (const float*)d_in[12];
    const float* W2   = (const float*)d_in[13];
    const float* A2   = (const float*)d_in[14];
    const float* b2   = (const float*)d_in[15];
    const float* eta2 = (const float*)d_in[16];
    const float* g2   = (const float*)d_in[17];
    const float* be2  = (const float*)d_in[18];
    const float* hw   = (const float*)d_in[19];
    const float* hbod = (const float*)d_in[20];
    float* out = (float*)d_out;

    char* w = (char*)d_ws;
    unsigned short* hb  = (unsigned short*)(w + 0);          // 20971520
    unsigned short* Wb0 = (unsigned short*)(w + 20971520);   // 5242880
    unsigned short* Sb0 = (unsigned short*)(w + 26214400);   // 5242880
    float* Py   = (float*)(w + 31457280);                    // 16777216
    float* Pp   = (float*)(w + 48234496);                    // 16777216
    float* W1T  = (float*)(w + 65011712);                    // 131072
    float* S1T  = (float*)(w + 65142784);                    // 131072
    float* W2T  = (float*)(w + 65273856);                    // 32768
    float* S2T  = (float*)(w + 65306624);                    // 32768
    float* hnm  = (float*)(w + 65339392);                    // 4096
    unsigned int* idxT = (unsigned int*)(w + 65343488);      // 40960 (10001 u32)
    // total = 65384448 bytes

    hipLaunchKernelGGL(init_tables_kernel, dim3(40), dim3(256), 0, stream, idxT);
    hipLaunchKernelGGL(fft_prep_kernel, dim3(3804), dim3(512), 0, stream,
                       x, hb, hnm, W0, A0, Wb0, Sb0, W1, A1, W2, A2, W1T, S1T, W2T, S2T,
                       idxT);
    hipLaunchKernelGGL(gemm0_kernel, dim3(512), dim3(256), 0, stream, hb, Wb0, Sb0, Py, Pp);
    hipLaunchKernelGGL(combine_tail_kernel, dim3(512), dim3(256), 0, stream, Py, Pp, hnm,
                       b0, eta0, g0, be0, W1T, S1T, b1, eta1, g1, be1,
                       W2T, S2T, b2, eta2, g2, be2, hw, hbod, out);
}